// Round 18
// baseline (286.004 us; speedup 1.0000x reference)
//
#include <hip/hip_runtime.h>
#include <math.h>

#define NPOS 131072  // 8*128*128 spatial positions per (b, channel)
#define GC 128       // gram chunks per (b,head); chunk = 1024 positions

typedef __attribute__((ext_vector_type(8))) short short8v;  // 8 bf16 (4 VGPR)
typedef __attribute__((ext_vector_type(4))) float f32x4;    // 4 fp32 acc

// split fp32 -> bf16 hi + bf16 lo (x ~= hi + lo, lo residual ~2^-16 |x|)
__device__ __forceinline__ void bf16split(float x, unsigned short& hi, unsigned short& lo) {
  unsigned u = __float_as_uint(x);
  hi = (unsigned short)(u >> 16);
  float hif = __uint_as_float(u & 0xffff0000u);
  float l = x - hif;  // exact
  lo = (unsigned short)(__float_as_uint(l) >> 16);
}

// ---------------------------------------------------------------------------
// k_prep: split w_qkv [192 out][64 in] into A-fragment-layout bf16 hi/lo.
// Frag element (g,ot,ks,l,j) <-> W[g*64 + ot*16 + (l&15)][ks*32 + (l>>4)*8 + j].
// ---------------------------------------------------------------------------
__global__ void k_prep(const float* __restrict__ w_qkv, unsigned short* __restrict__ whi,
                       unsigned short* __restrict__ wlo) {
  int idx = blockIdx.x * 256 + threadIdx.x;
  if (idx < 12288) {
    int j = idx & 7, l = (idx >> 3) & 63, ks = (idx >> 9) & 1, ot = (idx >> 10) & 3,
        g = idx >> 12;
    int out = ot * 16 + (l & 15);
    int k = ks * 32 + (l >> 4) * 8 + j;
    bf16split(w_qkv[(g * 64 + out) * 64 + k], whi[idx], wlo[idx]);
  }
}

// compute one 64-pos tile from LDS: 4 p-tiles x {16 ds_read, split, 6 MFMA, 4 st}
__device__ __forceinline__ void pw_compute(const float (*xl)[66], const short8v* ahi,
                                           const short8v* alo, float* __restrict__ ob0,
                                           int lane) {
  const int prow = lane & 15, kgrp = lane >> 4;
#pragma unroll
  for (int pt = 0; pt < 4; ++pt) {
    const int pos = pt * 16 + prow;
    short8v bh[2], bl[2];
#pragma unroll
    for (int ks = 0; ks < 2; ++ks)
#pragma unroll
      for (int j = 0; j < 8; ++j) {
        unsigned short h, lo16;
        bf16split(xl[ks * 32 + kgrp * 8 + j][pos], h, lo16);
        bh[ks][j] = (short)h;
        bl[ks][j] = (short)lo16;
      }
    f32x4 D = {0.f, 0.f, 0.f, 0.f};
#pragma unroll
    for (int ks = 0; ks < 2; ++ks) {
      D = __builtin_amdgcn_mfma_f32_16x16x32_bf16(ahi[ks], bh[ks], D, 0, 0, 0);
      D = __builtin_amdgcn_mfma_f32_16x16x32_bf16(ahi[ks], bl[ks], D, 0, 0, 0);
      D = __builtin_amdgcn_mfma_f32_16x16x32_bf16(alo[ks], bh[ks], D, 0, 0, 0);
    }
    float* ob = ob0 + pos;
#pragma unroll
    for (int jj = 0; jj < 4; ++jj) ob[(size_t)jj * NPOS] = D[jj];
  }
}

// ---------------------------------------------------------------------------
// k_pw_mfma: pre[b][o][p] = sum_k W[o][k] x[b][k][p] on the matrix pipe.
// T14 async-stage 2-tile double-buffer (r15/r16 both stuck at 42us with
// serial stage->wait->compute; tile B's HBM latency now hides under tile A's
// compute). Block = 128 positions (2 x 64-tiles); wave wid owns o-tile
// ot=wid. LDS [64][66] (2-way-only conflicts = free, m136).
// grid (1024, 2), block 256.
// ---------------------------------------------------------------------------
__global__ __launch_bounds__(256) void k_pw_mfma(const float* __restrict__ x,
                                                 const unsigned short* __restrict__ whi,
                                                 const unsigned short* __restrict__ wlo,
                                                 float* __restrict__ pre) {
  const int b = blockIdx.y;
  const int lane = threadIdx.x & 63;
  const int ot = threadIdx.x >> 6;   // wave id = o-tile
  const int p0 = blockIdx.x * 128;
  __shared__ float xl[64][66];
  short8v ahi[2], alo[2];
#pragma unroll
  for (int ks = 0; ks < 2; ++ks) {
    int fi = ((ot * 2 + ks) * 64 + lane) * 8;
    ahi[ks] = *(const short8v*)&whi[fi];
    alo[ks] = *(const short8v*)&wlo[fi];
  }
  const float* xb = x + ((size_t)b * 64) * NPOS + p0;
  const int tid = threadIdx.x;
  const int ch = tid >> 4, f4 = tid & 15;  // each thread owns (ch, f4) slot x4 rounds
  // stage tile A (positions 0..63)
#pragma unroll
  for (int r = 0; r < 4; ++r) {
    int ch2 = (r * 256 + tid) >> 4;
    float4 g = *(const float4*)&xb[(size_t)ch2 * NPOS + f4 * 4];
    *(float4*)&xl[ch2][f4 * 4] = g;
  }
  __syncthreads();
  // issue tile B loads (positions 64..127) into regs — overlap with A compute
  float4 xf[4];
#pragma unroll
  for (int r = 0; r < 4; ++r) {
    int ch2 = (r * 256 + tid) >> 4;
    xf[r] = *(const float4*)&xb[(size_t)ch2 * NPOS + 64 + f4 * 4];
  }
  float* ob0 = pre + ((size_t)b * 64 + ot * 16 + (lane >> 4) * 4) * NPOS + p0;
  pw_compute(xl, ahi, alo, ob0, lane);
  __syncthreads();  // all waves done reading tile A
#pragma unroll
  for (int r = 0; r < 4; ++r) {
    int ch2 = (r * 256 + tid) >> 4;
    *(float4*)&xl[ch2][f4 * 4] = xf[r];
  }
  __syncthreads();
  pw_compute(xl, ahi, alo, ob0 + 64, lane);
}

// ---------------------------------------------------------------------------
// stage_tile: one channel's halo tile -> LDS t[10][10][40]. float4 center,
// scalar edges, zero d-halo planes.
// ---------------------------------------------------------------------------
__device__ __forceinline__ void stage_tile(float (*t)[10][40], const float* __restrict__ in,
                                           int h0, int w0, int tid) {
  for (int i = tid; i < 800; i += 256) {
    int j = i & 7, row = i >> 3;
    int h = row % 10, dpl = row / 10;
    int dd = dpl - 1, hh = h0 + h - 1;
    float4 v = make_float4(0.f, 0.f, 0.f, 0.f);
    if (dd >= 0 && dd < 8 && hh >= 0 && hh < 128)
      v = *(const float4*)&in[((size_t)dd * 128 + hh) * 128 + (w0 + j * 4)];
    *(float4*)&t[dpl][h][4 + j * 4] = v;
  }
  for (int i = tid; i < 200; i += 256) {
    int side = i & 1, row = i >> 1;
    int h = row % 10, dpl = row / 10;
    int dd = dpl - 1, hh = h0 + h - 1;
    int ww = side ? (w0 + 32) : (w0 - 1);
    float v = 0.f;
    if (dd >= 0 && dd < 8 && hh >= 0 && hh < 128 && ww >= 0 && ww < 128)
      v = in[((size_t)dd * 128 + hh) * 128 + ww];
    t[dpl][h][side ? 36 : 3] = v;
  }
}

// ---------------------------------------------------------------------------
// conv_droll: d-rolling 3x3x3 conv: 90 LDS reads, 216 FMA for 8 d-outputs.
// ---------------------------------------------------------------------------
__device__ __forceinline__ void conv_droll(const float (*t)[10][40], const float* wk,
                                           int hl, int wl, float* acc) {
#pragma unroll
  for (int d = 0; d < 8; ++d) acc[d] = 0.f;
#pragma unroll
  for (int dpl = 0; dpl < 10; ++dpl) {
#pragma unroll
    for (int kh = 0; kh < 3; ++kh) {
#pragma unroll
      for (int kw = 0; kw < 3; ++kw) {
        float f = t[dpl][hl + kh][3 + wl + kw];
#pragma unroll
        for (int kd = 0; kd < 3; ++kd) {
          const int d = dpl - kd;
          if (d >= 0 && d < 8)
            acc[d] = fmaf(f, wk[(kd * 3 + kh) * 3 + kw], acc[d]);
        }
      }
    }
  }
}

// ---------------------------------------------------------------------------
// k_dw: depthwise 3x3x3 SAME on a 64-channel group. Flat grid 8192,
// XCD-swizzled. block (32, 8). Optional sum-of-squares partials -> nsq.
// ---------------------------------------------------------------------------
__global__ __launch_bounds__(256) void k_dw(const float* __restrict__ pre,
                                            const float* __restrict__ w_dw,
                                            float* __restrict__ conv,
                                            float* __restrict__ nsq, int g) {
  const int id = blockIdx.x;
  const int sid = (id & 7) * 1024 + (id >> 3);
  const int z = sid >> 6, r = sid & 63, by = r >> 2, bx = r & 3;
  const int b = z >> 6;
  const int c = z & 63;
  const int h0 = by * 8;
  const int w0 = bx * 32;
  __shared__ float t[10][10][40];
  __shared__ float red[4];
  const int tid = threadIdx.y * 32 + threadIdx.x;
  stage_tile(t, pre + ((size_t)b * 64 + c) * NPOS, h0, w0, tid);
  float wk[27];
#pragma unroll
  for (int i = 0; i < 27; ++i) wk[i] = w_dw[(g * 64 + c) * 27 + i];
  __syncthreads();
  const int wl = threadIdx.x, hl = threadIdx.y;
  float acc[8];
  conv_droll(t, wk, hl, wl, acc);
  float* outp = conv + ((size_t)b * 64 + c) * NPOS + (size_t)(h0 + hl) * 128 + (w0 + wl);
  float nsum = 0.f;
#pragma unroll
  for (int d = 0; d < 8; ++d) {
    outp[(size_t)d * 16384] = acc[d];
    nsum = fmaf(acc[d], acc[d], nsum);
  }
  if (nsq) {
    const int lane = tid & 63, wv = tid >> 6;
    float v = nsum;
    v += __shfl_down(v, 32); v += __shfl_down(v, 16); v += __shfl_down(v, 8);
    v += __shfl_down(v, 4);  v += __shfl_down(v, 2);  v += __shfl_down(v, 1);
    if (lane == 0) red[wv] = v;
    __syncthreads();
    if (tid == 0) {
      const int blk = by * 4 + bx;
      nsq[((size_t)b * 64 + c) * 64 + blk] = red[0] + red[1] + red[2] + red[3];
    }
  }
}

// ---------------------------------------------------------------------------
// k_gramS: streaming Gram reduce, S[8][8] only (norms come from k_dw).
// grid (GC, 16 bh), block 256; 4 unrolled iterations of {16 loads -> 64 FMA};
// asm guards pin S. Butterfly-split reduction (63 shuffles) -> lane l holds
// wave sum of S[bitrev6(l)]. partialS[(bh*GC + chunk)*64 + c*8+e].
// ---------------------------------------------------------------------------
__global__ __launch_bounds__(256) void k_gramS(const float* __restrict__ qconv,
                                               const float* __restrict__ kconv,
                                               float* __restrict__ partialS) {
  const int chunk = blockIdx.x;   // 0..GC-1
  const int bh = blockIdx.y;      // 0..15
  const int b = bh >> 3, head = bh & 7;
  const int tid = threadIdx.x;
  const size_t base = ((size_t)b * 64 + head * 8) * NPOS + (size_t)chunk * 1024 + tid;
  const float* qb = qconv + base;
  const float* kb = kconv + base;
  float S[64];
#pragma unroll
  for (int i = 0; i < 64; ++i) S[i] = 0.f;
#pragma unroll
  for (int it = 0; it < 4; ++it) {
    const size_t off = (size_t)it * 256;
    float qv[8], kv[8];
#pragma unroll
    for (int c = 0; c < 8; ++c) qv[c] = qb[(size_t)c * NPOS + off];
#pragma unroll
    for (int e = 0; e < 8; ++e) kv[e] = kb[(size_t)e * NPOS + off];
#pragma unroll
    for (int c = 0; c < 8; ++c)
#pragma unroll
      for (int e = 0; e < 8; ++e) S[c * 8 + e] = fmaf(qv[c], kv[e], S[c * 8 + e]);
  }
#pragma unroll
  for (int i = 0; i < 64; ++i) asm volatile("" : "+v"(S[i]));  // keep S material

  const int lane = tid & 63, wv = tid >> 6;
#define BSTEP(src, dst, n, s)                                        \
  {                                                                  \
    const bool hi_ = (lane >> (s)) & 1;                              \
    _Pragma("unroll")                                                \
    for (int i_ = 0; i_ < (n); ++i_) {                               \
      float send_ = hi_ ? src[i_] : src[i_ + (n)];                   \
      float mine_ = hi_ ? src[i_ + (n)] : src[i_];                   \
      dst[i_] = mine_ + __shfl_xor(send_, 1 << (s));                 \
    }                                                                \
  }
  float v32[32], v16[16], v8[8], v4[4], v2[2], v1[1];
  BSTEP(S,   v32, 32, 0)
  BSTEP(v32, v16, 16, 1)
  BSTEP(v16, v8,   8, 2)
  BSTEP(v8,  v4,   4, 3)
  BSTEP(v4,  v2,   2, 4)
  BSTEP(v2,  v1,   1, 5)
#undef BSTEP
  const int idx = ((lane & 1) << 5) | ((lane & 2) << 3) | ((lane & 4) << 1) |
                  ((lane & 8) >> 1) | ((lane & 16) >> 3) | ((lane & 32) >> 5);
  __shared__ float red[4][64];
  red[wv][idx] = v1[0];
  __syncthreads();
  if (tid < 64) {
    float s = red[0][tid] + red[1][tid] + red[2][tid] + red[3][tid];
    partialS[((size_t)bh * GC + chunk) * 64 + tid] = s;
  }
}

// ---------------------------------------------------------------------------
// k_attn: reduce partialS (GC chunks) + nqp/nkp (64 spatial blocks),
// l2-normalize, temperature, softmax -> A[bh][c][e]. grid 16, block 128.
// ---------------------------------------------------------------------------
__global__ void k_attn(const float* __restrict__ partialS, const float* __restrict__ nqp,
                       const float* __restrict__ nkp, const float* __restrict__ temp,
                       float* __restrict__ A) {
  const int bh = blockIdx.x;
  const int b = bh >> 3, head = bh & 7;
  const int tid = threadIdx.x;
  __shared__ float sums[80];
  if (tid < 64) {
    float s = 0.f;
    const float* pp = partialS + (size_t)bh * GC * 64 + tid;
    for (int j = 0; j < GC; ++j) s += pp[j * 64];
    sums[tid] = s;  // S[c*8+e]
  } else if (tid < 72) {
    const int e = tid - 64;
    float s = 0.f;
    const float* pp = nkp + ((size_t)b * 64 + head * 8 + e) * 64;
    for (int j = 0; j < 64; ++j) s += pp[j];
    sums[64 + e] = s;  // nk[e]
  } else if (tid < 80) {
    const int c = tid - 72;
    float s = 0.f;
    const float* pp = nqp + ((size_t)b * 64 + head * 8 + c) * 64;
    for (int j = 0; j < 64; ++j) s += pp[j];
    sums[72 + c] = s;  // nq[c]
  }
  __syncthreads();
  if (tid < 8) {
    const int c = tid;
    float tp = temp[head];
    float qd = fmaxf(sqrtf(sums[72 + c]), 1e-12f);
    float vals[8];
    float mx = -1e30f;
#pragma unroll
    for (int e = 0; e < 8; ++e) {
      float kd = fmaxf(sqrtf(sums[64 + e]), 1e-12f);
      vals[e] = sums[c * 8 + e] / (qd * kd) * tp;
      mx = fmaxf(mx, vals[e]);
    }
    float den = 0.f;
#pragma unroll
    for (int e = 0; e < 8; ++e) { vals[e] = expf(vals[e] - mx); den += vals[e]; }
#pragma unroll
    for (int e = 0; e < 8; ++e) A[bh * 64 + c * 8 + e] = vals[e] / den;
  }
}

// ---------------------------------------------------------------------------
// k_M: M_b = W_proj x blockdiag(softmax A_b), written directly in A-fragment
// bf16 hi/lo layout for k_out_mfma. grid 2, block 256.
// ---------------------------------------------------------------------------
__global__ void k_M(const float* __restrict__ w_proj, const float* __restrict__ A,
                    unsigned short* __restrict__ Mhi, unsigned short* __restrict__ Mlo) {
  const int b = blockIdx.x;
  for (int e = threadIdx.x; e < 4096; e += 256) {
    int j = e & 7, l = (e >> 3) & 63, ks = (e >> 9) & 1, ot = (e >> 10) & 3;
    int out = ot * 16 + (l & 15);
    int gch = ks * 32 + (l >> 4) * 8 + j;
    int hg = gch >> 3, jj = gch & 7;
    float s = 0.f;
#pragma unroll
    for (int i = 0; i < 8; ++i)
      s += w_proj[out * 64 + hg * 8 + i] * A[(b * 8 + hg) * 64 + i * 8 + jj];
    bf16split(s, Mhi[b * 4096 + e], Mlo[b * 4096 + e]);
  }
}

// ---------------------------------------------------------------------------
// k_out_mfma: out[b][o][p] = sum_g M_b[o][g] vconv[b][g][p]. Same 2-tile
// double-buffered MFMA structure as k_pw_mfma. grid (1024, 2), block 256.
// ---------------------------------------------------------------------------
__global__ __launch_bounds__(256) void k_out_mfma(const float* __restrict__ vconv,
                                                  const unsigned short* __restrict__ Mhi,
                                                  const unsigned short* __restrict__ Mlo,
                                                  float* __restrict__ out) {
  const int b = blockIdx.y;
  const int lane = threadIdx.x & 63;
  const int ot = threadIdx.x >> 6;
  const int p0 = blockIdx.x * 128;
  __shared__ float xl[64][66];
  short8v ahi[2], alo[2];
#pragma unroll
  for (int ks = 0; ks < 2; ++ks) {
    int fi = b * 4096 + ((ot * 2 + ks) * 64 + lane) * 8;
    ahi[ks] = *(const short8v*)&Mhi[fi];
    alo[ks] = *(const short8v*)&Mlo[fi];
  }
  const float* vb = vconv + ((size_t)b * 64) * NPOS + p0;
  const int tid = threadIdx.x;
  const int f4 = tid & 15;
#pragma unroll
  for (int r = 0; r < 4; ++r) {
    int ch2 = (r * 256 + tid) >> 4;
    float4 g = *(const float4*)&vb[(size_t)ch2 * NPOS + f4 * 4];
    *(float4*)&xl[ch2][f4 * 4] = g;
  }
  __syncthreads();
  float4 xf[4];
#pragma unroll
  for (int r = 0; r < 4; ++r) {
    int ch2 = (r * 256 + tid) >> 4;
    xf[r] = *(const float4*)&vb[(size_t)ch2 * NPOS + 64 + f4 * 4];
  }
  float* ob0 = out + ((size_t)b * 64 + ot * 16 + (lane >> 4) * 4) * NPOS + p0;
  pw_compute(xl, ahi, alo, ob0, lane);
  __syncthreads();
#pragma unroll
  for (int r = 0; r < 4; ++r) {
    int ch2 = (r * 256 + tid) >> 4;
    *(float4*)&xl[ch2][f4 * 4] = xf[r];
  }
  __syncthreads();
  pw_compute(xl, ahi, alo, ob0 + 64, lane);
}

extern "C" void kernel_launch(void* const* d_in, const int* in_sizes, int n_in,
                              void* d_out, int out_size, void* d_ws, size_t ws_size,
                              hipStream_t stream) {
  const float* x      = (const float*)d_in[0];
  const float* w_qkv  = (const float*)d_in[1];
  const float* w_dw   = (const float*)d_in[2];
  const float* temp   = (const float*)d_in[3];
  const float* w_proj = (const float*)d_in[4];
  float* out = (float*)d_out;   // also used as pre-conv staging per group
  float* ws  = (float*)d_ws;

  // workspace layout — ~135 MB (r16 layout; produce->consume order keeps each
  // 67 MB tensor L3-resident between stages — r17 proved fusing breaks this)
  float* conv_buf = ws;                       // qconv, later vconv (67 MB)
  float* kconv    = conv_buf + 16777216ull;   // 67 MB
  float* nqp      = kconv + 16777216ull;      // 8,192
  float* nkp      = nqp + 8192ull;            // 8,192
  float* partialS = nkp + 8192ull;            // 16*GC*64 = 131,072
  float* Abuf     = partialS + 131072ull;     // 1,024
  unsigned short* whi = (unsigned short*)(Abuf + 1024ull);  // 12,288 us
  unsigned short* wlo = whi + 12288ull;                     // 12,288 us
  unsigned short* Mhi = wlo + 12288ull;                     // 8,192 us
  unsigned short* Mlo = Mhi + 8192ull;                      // 8,192 us

  k_prep<<<48, 256, 0, stream>>>(w_qkv, whi, wlo);
  // q group: pointwise (MFMA) -> d_out, depthwise -> conv_buf (+ nq partials)
  k_pw_mfma<<<dim3(1024, 2), 256, 0, stream>>>(x, whi, wlo, out);
  k_dw<<<8192, dim3(32, 8), 0, stream>>>(out, w_dw, conv_buf, nqp, 0);
  // k group: pointwise -> d_out, depthwise -> kconv (+ nk partials)
  k_pw_mfma<<<dim3(1024, 2), 256, 0, stream>>>(x, whi + 4096, wlo + 4096, out);
  k_dw<<<8192, dim3(32, 8), 0, stream>>>(out, w_dw, kconv, nkp, 1);
  // Gram + attention matrix + folded projection matrix (frag layout)
  k_gramS<<<dim3(GC, 16), 256, 0, stream>>>(conv_buf, kconv, partialS);
  k_attn<<<16, 128, 0, stream>>>(partialS, nqp, nkp, temp, Abuf);
  k_M<<<2, 256, 0, stream>>>(w_proj, Abuf, Mhi, Mlo);
  // v group: pointwise -> d_out, depthwise -> conv_buf, apply M (MFMA) -> d_out
  k_pw_mfma<<<dim3(1024, 2), 256, 0, stream>>>(x, whi + 8192, wlo + 8192, out);
  k_dw<<<8192, dim3(32, 8), 0, stream>>>(out, w_dw, conv_buf, nullptr, 2);
  k_out_mfma<<<dim3(1024, 2), 256, 0, stream>>>(conv_buf, Mhi, Mlo, out);
}

// Round 19
// 231.889 us; speedup vs baseline: 1.2334x; 1.2334x over previous
//
#include <hip/hip_runtime.h>
#include <math.h>

#define NPOS 131072  // 8*128*128 spatial positions per (b, channel)
#define GC 128       // gram chunks per (b,head); chunk = 1024 positions

typedef __attribute__((ext_vector_type(8))) short short8v;  // 8 bf16 (4 VGPR)
typedef __attribute__((ext_vector_type(4))) float f32x4;    // 4 fp32 acc
typedef __attribute__((address_space(3))) unsigned int lds_u32;
typedef const __attribute__((address_space(1))) unsigned int glb_u32;

// split fp32 -> bf16 hi + bf16 lo (x ~= hi + lo, lo residual ~2^-16 |x|)
__device__ __forceinline__ void bf16split(float x, unsigned short& hi, unsigned short& lo) {
  unsigned u = __float_as_uint(x);
  hi = (unsigned short)(u >> 16);
  float hif = __uint_as_float(u & 0xffff0000u);
  float l = x - hif;  // exact
  lo = (unsigned short)(__float_as_uint(l) >> 16);
}

// ---------------------------------------------------------------------------
// k_prep: split w_qkv [192 out][64 in] into A-fragment-layout bf16 hi/lo.
// Frag element (g,ot,ks,l,j) <-> W[g*64 + ot*16 + (l&15)][ks*32 + (l>>4)*8 + j].
// ---------------------------------------------------------------------------
__global__ void k_prep(const float* __restrict__ w_qkv, unsigned short* __restrict__ whi,
                       unsigned short* __restrict__ wlo) {
  int idx = blockIdx.x * 256 + threadIdx.x;
  if (idx < 12288) {
    int j = idx & 7, l = (idx >> 3) & 63, ks = (idx >> 9) & 1, ot = (idx >> 10) & 3,
        g = idx >> 12;
    int out = ot * 16 + (l & 15);
    int k = ks * 32 + (l >> 4) * 8 + j;
    bf16split(w_qkv[(g * 64 + out) * 64 + k], whi[idx], wlo[idx]);
  }
}

// ---------------------------------------------------------------------------
// stage_async: DMA one 64ch x 64pos x-tile into an UNPADDED [64][64] LDS buf
// via global_load_lds width=16 (common-mistake #1: compiler never auto-emits).
// LDS dest for lane = uniform base + lane*16 (linear layout requirement, m104).
// ---------------------------------------------------------------------------
__device__ __forceinline__ void stage_async(const float* __restrict__ gb, float* lbuf,
                                            int tid) {
#pragma unroll
  for (int r = 0; r < 4; ++r) {
    int idx = r * 256 + tid;            // 0..1023: ch = idx>>4, f4 = idx&15
    int ch = idx >> 4, f4 = idx & 15;
    __builtin_amdgcn_global_load_lds((glb_u32*)(gb + (size_t)ch * NPOS + f4 * 4),
                                     (lds_u32*)(lbuf + idx * 4), 16, 0, 0);
  }
}

// compute one 64-pos tile from LDS: 4 p-tiles x {16 ds_read, split, 6 MFMA, 4 st}
__device__ __forceinline__ void pw_compute(const float (*xl)[64], const short8v* ahi,
                                           const short8v* alo, float* __restrict__ ob0,
                                           int lane) {
  const int prow = lane & 15, kgrp = lane >> 4;
#pragma unroll
  for (int pt = 0; pt < 4; ++pt) {
    const int pos = pt * 16 + prow;
    short8v bh[2], bl[2];
#pragma unroll
    for (int ks = 0; ks < 2; ++ks)
#pragma unroll
      for (int j = 0; j < 8; ++j) {
        unsigned short h, lo16;
        bf16split(xl[ks * 32 + kgrp * 8 + j][pos], h, lo16);
        bh[ks][j] = (short)h;
        bl[ks][j] = (short)lo16;
      }
    f32x4 D = {0.f, 0.f, 0.f, 0.f};
#pragma unroll
    for (int ks = 0; ks < 2; ++ks) {
      D = __builtin_amdgcn_mfma_f32_16x16x32_bf16(ahi[ks], bh[ks], D, 0, 0, 0);
      D = __builtin_amdgcn_mfma_f32_16x16x32_bf16(ahi[ks], bl[ks], D, 0, 0, 0);
      D = __builtin_amdgcn_mfma_f32_16x16x32_bf16(alo[ks], bh[ks], D, 0, 0, 0);
    }
    float* ob = ob0 + pos;
#pragma unroll
    for (int jj = 0; jj < 4; ++jj) ob[(size_t)jj * NPOS] = D[jj];
  }
}

// ---------------------------------------------------------------------------
// k_pw_mfma: pre[b][o][p] = sum_k W[o][k] x[b][k][p] on the matrix pipe.
// T3 minimal 2-phase pipeline over 4 tiles/block: STAGE(next) via
// global_load_lds issued BEFORE compute(current); one barrier/tile drains.
// (r11-r18: every serial stage->drain->compute variant lands 42-55us; the
// per-tile stage latency was never overlapped.) LDS 2 x [64][64] unpadded
// (global_load_lds linear-dest requirement); ds_read 4-way conflicts = 1.58x
// on 16 reads/tile, minor. grid (512, 2), block 256.
// ---------------------------------------------------------------------------
__global__ __launch_bounds__(256) void k_pw_mfma(const float* __restrict__ x,
                                                 const unsigned short* __restrict__ whi,
                                                 const unsigned short* __restrict__ wlo,
                                                 float* __restrict__ pre) {
  const int b = blockIdx.y;
  const int lane = threadIdx.x & 63;
  const int ot = threadIdx.x >> 6;   // wave id = o-tile
  const int p0 = blockIdx.x * 256;   // 4 tiles x 64 positions
  __shared__ __align__(16) float xl[2][64][64];
  short8v ahi[2], alo[2];
#pragma unroll
  for (int ks = 0; ks < 2; ++ks) {
    int fi = ((ot * 2 + ks) * 64 + lane) * 8;
    ahi[ks] = *(const short8v*)&whi[fi];
    alo[ks] = *(const short8v*)&wlo[fi];
  }
  const float* xb = x + ((size_t)b * 64) * NPOS + p0;
  const int tid = threadIdx.x;
  float* ob0 = pre + ((size_t)b * 64 + ot * 16 + (lane >> 4) * 4) * NPOS + p0;
  stage_async(xb, &xl[0][0][0], tid);
  __syncthreads();
#pragma unroll
  for (int t = 0; t < 4; ++t) {
    if (t < 3) stage_async(xb + (t + 1) * 64, &xl[(t + 1) & 1][0][0], tid);
    pw_compute(xl[t & 1], ahi, alo, ob0 + t * 64, lane);
    __syncthreads();  // drains stage(t+1) (overlapped with compute) + readers
  }
}

// ---------------------------------------------------------------------------
// stage_tile: one channel's halo tile -> LDS t[10][10][40]. float4 center,
// scalar edges, zero d-halo planes.
// ---------------------------------------------------------------------------
__device__ __forceinline__ void stage_tile(float (*t)[10][40], const float* __restrict__ in,
                                           int h0, int w0, int tid) {
  for (int i = tid; i < 800; i += 256) {
    int j = i & 7, row = i >> 3;
    int h = row % 10, dpl = row / 10;
    int dd = dpl - 1, hh = h0 + h - 1;
    float4 v = make_float4(0.f, 0.f, 0.f, 0.f);
    if (dd >= 0 && dd < 8 && hh >= 0 && hh < 128)
      v = *(const float4*)&in[((size_t)dd * 128 + hh) * 128 + (w0 + j * 4)];
    *(float4*)&t[dpl][h][4 + j * 4] = v;
  }
  for (int i = tid; i < 200; i += 256) {
    int side = i & 1, row = i >> 1;
    int h = row % 10, dpl = row / 10;
    int dd = dpl - 1, hh = h0 + h - 1;
    int ww = side ? (w0 + 32) : (w0 - 1);
    float v = 0.f;
    if (dd >= 0 && dd < 8 && hh >= 0 && hh < 128 && ww >= 0 && ww < 128)
      v = in[((size_t)dd * 128 + hh) * 128 + ww];
    t[dpl][h][side ? 36 : 3] = v;
  }
}

// ---------------------------------------------------------------------------
// conv_droll: d-rolling 3x3x3 conv: 90 LDS reads, 216 FMA for 8 d-outputs.
// ---------------------------------------------------------------------------
__device__ __forceinline__ void conv_droll(const float (*t)[10][40], const float* wk,
                                           int hl, int wl, float* acc) {
#pragma unroll
  for (int d = 0; d < 8; ++d) acc[d] = 0.f;
#pragma unroll
  for (int dpl = 0; dpl < 10; ++dpl) {
#pragma unroll
    for (int kh = 0; kh < 3; ++kh) {
#pragma unroll
      for (int kw = 0; kw < 3; ++kw) {
        float f = t[dpl][hl + kh][3 + wl + kw];
#pragma unroll
        for (int kd = 0; kd < 3; ++kd) {
          const int d = dpl - kd;
          if (d >= 0 && d < 8)
            acc[d] = fmaf(f, wk[(kd * 3 + kh) * 3 + kw], acc[d]);
        }
      }
    }
  }
}

// ---------------------------------------------------------------------------
// k_dw: depthwise 3x3x3 SAME on a 64-channel group. Flat grid 8192,
// XCD-swizzled. block (32, 8). Optional sum-of-squares partials -> nsq.
// ---------------------------------------------------------------------------
__global__ __launch_bounds__(256) void k_dw(const float* __restrict__ pre,
                                            const float* __restrict__ w_dw,
                                            float* __restrict__ conv,
                                            float* __restrict__ nsq, int g) {
  const int id = blockIdx.x;
  const int sid = (id & 7) * 1024 + (id >> 3);
  const int z = sid >> 6, r = sid & 63, by = r >> 2, bx = r & 3;
  const int b = z >> 6;
  const int c = z & 63;
  const int h0 = by * 8;
  const int w0 = bx * 32;
  __shared__ float t[10][10][40];
  __shared__ float red[4];
  const int tid = threadIdx.y * 32 + threadIdx.x;
  stage_tile(t, pre + ((size_t)b * 64 + c) * NPOS, h0, w0, tid);
  float wk[27];
#pragma unroll
  for (int i = 0; i < 27; ++i) wk[i] = w_dw[(g * 64 + c) * 27 + i];
  __syncthreads();
  const int wl = threadIdx.x, hl = threadIdx.y;
  float acc[8];
  conv_droll(t, wk, hl, wl, acc);
  float* outp = conv + ((size_t)b * 64 + c) * NPOS + (size_t)(h0 + hl) * 128 + (w0 + wl);
  float nsum = 0.f;
#pragma unroll
  for (int d = 0; d < 8; ++d) {
    outp[(size_t)d * 16384] = acc[d];
    nsum = fmaf(acc[d], acc[d], nsum);
  }
  if (nsq) {
    const int lane = tid & 63, wv = tid >> 6;
    float v = nsum;
    v += __shfl_down(v, 32); v += __shfl_down(v, 16); v += __shfl_down(v, 8);
    v += __shfl_down(v, 4);  v += __shfl_down(v, 2);  v += __shfl_down(v, 1);
    if (lane == 0) red[wv] = v;
    __syncthreads();
    if (tid == 0) {
      const int blk = by * 4 + bx;
      nsq[((size_t)b * 64 + c) * 64 + blk] = red[0] + red[1] + red[2] + red[3];
    }
  }
}

// ---------------------------------------------------------------------------
// k_gramS: streaming Gram reduce, S[8][8] only (norms come from k_dw).
// grid (GC, 16 bh), block 256; 4 unrolled iterations of {16 loads -> 64 FMA};
// asm guards pin S. Butterfly-split reduction (63 shuffles) -> lane l holds
// wave sum of S[bitrev6(l)]. partialS[(bh*GC + chunk)*64 + c*8+e].
// ---------------------------------------------------------------------------
__global__ __launch_bounds__(256) void k_gramS(const float* __restrict__ qconv,
                                               const float* __restrict__ kconv,
                                               float* __restrict__ partialS) {
  const int chunk = blockIdx.x;   // 0..GC-1
  const int bh = blockIdx.y;      // 0..15
  const int b = bh >> 3, head = bh & 7;
  const int tid = threadIdx.x;
  const size_t base = ((size_t)b * 64 + head * 8) * NPOS + (size_t)chunk * 1024 + tid;
  const float* qb = qconv + base;
  const float* kb = kconv + base;
  float S[64];
#pragma unroll
  for (int i = 0; i < 64; ++i) S[i] = 0.f;
#pragma unroll
  for (int it = 0; it < 4; ++it) {
    const size_t off = (size_t)it * 256;
    float qv[8], kv[8];
#pragma unroll
    for (int c = 0; c < 8; ++c) qv[c] = qb[(size_t)c * NPOS + off];
#pragma unroll
    for (int e = 0; e < 8; ++e) kv[e] = kb[(size_t)e * NPOS + off];
#pragma unroll
    for (int c = 0; c < 8; ++c)
#pragma unroll
      for (int e = 0; e < 8; ++e) S[c * 8 + e] = fmaf(qv[c], kv[e], S[c * 8 + e]);
  }
#pragma unroll
  for (int i = 0; i < 64; ++i) asm volatile("" : "+v"(S[i]));  // keep S material

  const int lane = tid & 63, wv = tid >> 6;
#define BSTEP(src, dst, n, s)                                        \
  {                                                                  \
    const bool hi_ = (lane >> (s)) & 1;                              \
    _Pragma("unroll")                                                \
    for (int i_ = 0; i_ < (n); ++i_) {                               \
      float send_ = hi_ ? src[i_] : src[i_ + (n)];                   \
      float mine_ = hi_ ? src[i_ + (n)] : src[i_];                   \
      dst[i_] = mine_ + __shfl_xor(send_, 1 << (s));                 \
    }                                                                \
  }
  float v32[32], v16[16], v8[8], v4[4], v2[2], v1[1];
  BSTEP(S,   v32, 32, 0)
  BSTEP(v32, v16, 16, 1)
  BSTEP(v16, v8,   8, 2)
  BSTEP(v8,  v4,   4, 3)
  BSTEP(v4,  v2,   2, 4)
  BSTEP(v2,  v1,   1, 5)
#undef BSTEP
  const int idx = ((lane & 1) << 5) | ((lane & 2) << 3) | ((lane & 4) << 1) |
                  ((lane & 8) >> 1) | ((lane & 16) >> 3) | ((lane & 32) >> 5);
  __shared__ float red[4][64];
  red[wv][idx] = v1[0];
  __syncthreads();
  if (tid < 64) {
    float s = red[0][tid] + red[1][tid] + red[2][tid] + red[3][tid];
    partialS[((size_t)bh * GC + chunk) * 64 + tid] = s;
  }
}

// ---------------------------------------------------------------------------
// k_attn: reduce partialS (GC chunks) + nqp/nkp (64 spatial blocks),
// l2-normalize, temperature, softmax -> A[bh][c][e]. grid 16, block 128.
// ---------------------------------------------------------------------------
__global__ void k_attn(const float* __restrict__ partialS, const float* __restrict__ nqp,
                       const float* __restrict__ nkp, const float* __restrict__ temp,
                       float* __restrict__ A) {
  const int bh = blockIdx.x;
  const int b = bh >> 3, head = bh & 7;
  const int tid = threadIdx.x;
  __shared__ float sums[80];
  if (tid < 64) {
    float s = 0.f;
    const float* pp = partialS + (size_t)bh * GC * 64 + tid;
    for (int j = 0; j < GC; ++j) s += pp[j * 64];
    sums[tid] = s;  // S[c*8+e]
  } else if (tid < 72) {
    const int e = tid - 64;
    float s = 0.f;
    const float* pp = nkp + ((size_t)b * 64 + head * 8 + e) * 64;
    for (int j = 0; j < 64; ++j) s += pp[j];
    sums[64 + e] = s;  // nk[e]
  } else if (tid < 80) {
    const int c = tid - 72;
    float s = 0.f;
    const float* pp = nqp + ((size_t)b * 64 + head * 8 + c) * 64;
    for (int j = 0; j < 64; ++j) s += pp[j];
    sums[72 + c] = s;  // nq[c]
  }
  __syncthreads();
  if (tid < 8) {
    const int c = tid;
    float tp = temp[head];
    float qd = fmaxf(sqrtf(sums[72 + c]), 1e-12f);
    float vals[8];
    float mx = -1e30f;
#pragma unroll
    for (int e = 0; e < 8; ++e) {
      float kd = fmaxf(sqrtf(sums[64 + e]), 1e-12f);
      vals[e] = sums[c * 8 + e] / (qd * kd) * tp;
      mx = fmaxf(mx, vals[e]);
    }
    float den = 0.f;
#pragma unroll
    for (int e = 0; e < 8; ++e) { vals[e] = expf(vals[e] - mx); den += vals[e]; }
#pragma unroll
    for (int e = 0; e < 8; ++e) A[bh * 64 + c * 8 + e] = vals[e] / den;
  }
}

// ---------------------------------------------------------------------------
// k_M: M_b = W_proj x blockdiag(softmax A_b), written directly in A-fragment
// bf16 hi/lo layout for k_out_mfma. grid 2, block 256.
// ---------------------------------------------------------------------------
__global__ void k_M(const float* __restrict__ w_proj, const float* __restrict__ A,
                    unsigned short* __restrict__ Mhi, unsigned short* __restrict__ Mlo) {
  const int b = blockIdx.x;
  for (int e = threadIdx.x; e < 4096; e += 256) {
    int j = e & 7, l = (e >> 3) & 63, ks = (e >> 9) & 1, ot = (e >> 10) & 3;
    int out = ot * 16 + (l & 15);
    int gch = ks * 32 + (l >> 4) * 8 + j;
    int hg = gch >> 3, jj = gch & 7;
    float s = 0.f;
#pragma unroll
    for (int i = 0; i < 8; ++i)
      s += w_proj[out * 64 + hg * 8 + i] * A[(b * 8 + hg) * 64 + i * 8 + jj];
    bf16split(s, Mhi[b * 4096 + e], Mlo[b * 4096 + e]);
  }
}

// ---------------------------------------------------------------------------
// k_out_mfma: out[b][o][p] = sum_g M_b[o][g] vconv[b][g][p]. Same 4-tile
// global_load_lds pipeline as k_pw_mfma. grid (512, 2), block 256.
// ---------------------------------------------------------------------------
__global__ __launch_bounds__(256) void k_out_mfma(const float* __restrict__ vconv,
                                                  const unsigned short* __restrict__ Mhi,
                                                  const unsigned short* __restrict__ Mlo,
                                                  float* __restrict__ out) {
  const int b = blockIdx.y;
  const int lane = threadIdx.x & 63;
  const int ot = threadIdx.x >> 6;
  const int p0 = blockIdx.x * 256;
  __shared__ __align__(16) float xl[2][64][64];
  short8v ahi[2], alo[2];
#pragma unroll
  for (int ks = 0; ks < 2; ++ks) {
    int fi = b * 4096 + ((ot * 2 + ks) * 64 + lane) * 8;
    ahi[ks] = *(const short8v*)&Mhi[fi];
    alo[ks] = *(const short8v*)&Mlo[fi];
  }
  const float* vb = vconv + ((size_t)b * 64) * NPOS + p0;
  const int tid = threadIdx.x;
  float* ob0 = out + ((size_t)b * 64 + ot * 16 + (lane >> 4) * 4) * NPOS + p0;
  stage_async(vb, &xl[0][0][0], tid);
  __syncthreads();
#pragma unroll
  for (int t = 0; t < 4; ++t) {
    if (t < 3) stage_async(vb + (t + 1) * 64, &xl[(t + 1) & 1][0][0], tid);
    pw_compute(xl[t & 1], ahi, alo, ob0 + t * 64, lane);
    __syncthreads();
  }
}

extern "C" void kernel_launch(void* const* d_in, const int* in_sizes, int n_in,
                              void* d_out, int out_size, void* d_ws, size_t ws_size,
                              hipStream_t stream) {
  const float* x      = (const float*)d_in[0];
  const float* w_qkv  = (const float*)d_in[1];
  const float* w_dw   = (const float*)d_in[2];
  const float* temp   = (const float*)d_in[3];
  const float* w_proj = (const float*)d_in[4];
  float* out = (float*)d_out;   // also used as pre-conv staging per group
  float* ws  = (float*)d_ws;

  // workspace layout — ~135 MB (r16 layout; produce->consume order keeps each
  // 67 MB tensor L3-resident between stages — r17 proved fusing breaks this)
  float* conv_buf = ws;                       // qconv, later vconv (67 MB)
  float* kconv    = conv_buf + 16777216ull;   // 67 MB
  float* nqp      = kconv + 16777216ull;      // 8,192
  float* nkp      = nqp + 8192ull;            // 8,192
  float* partialS = nkp + 8192ull;            // 16*GC*64 = 131,072
  float* Abuf     = partialS + 131072ull;     // 1,024
  unsigned short* whi = (unsigned short*)(Abuf + 1024ull);  // 12,288 us
  unsigned short* wlo = whi + 12288ull;                     // 12,288 us
  unsigned short* Mhi = wlo + 12288ull;                     // 8,192 us
  unsigned short* Mlo = Mhi + 8192ull;                      // 8,192 us

  k_prep<<<48, 256, 0, stream>>>(w_qkv, whi, wlo);
  // q group: pointwise (MFMA) -> d_out, depthwise -> conv_buf (+ nq partials)
  k_pw_mfma<<<dim3(512, 2), 256, 0, stream>>>(x, whi, wlo, out);
  k_dw<<<8192, dim3(32, 8), 0, stream>>>(out, w_dw, conv_buf, nqp, 0);
  // k group: pointwise -> d_out, depthwise -> kconv (+ nk partials)
  k_pw_mfma<<<dim3(512, 2), 256, 0, stream>>>(x, whi + 4096, wlo + 4096, out);
  k_dw<<<8192, dim3(32, 8), 0, stream>>>(out, w_dw, kconv, nkp, 1);
  // Gram + attention matrix + folded projection matrix (frag layout)
  k_gramS<<<dim3(GC, 16), 256, 0, stream>>>(conv_buf, kconv, partialS);
  k_attn<<<16, 128, 0, stream>>>(partialS, nqp, nkp, temp, Abuf);
  k_M<<<2, 256, 0, stream>>>(w_proj, Abuf, Mhi, Mlo);
  // v group: pointwise -> d_out, depthwise -> conv_buf, apply M (MFMA) -> d_out
  k_pw_mfma<<<dim3(512, 2), 256, 0, stream>>>(x, whi + 8192, wlo + 8192, out);
  k_dw<<<8192, dim3(32, 8), 0, stream>>>(out, w_dw, conv_buf, nullptr, 2);
  k_out_mfma<<<dim3(512, 2), 256, 0, stream>>>(conv_buf, Mhi, Mlo, out);
}

// Round 20
// 222.831 us; speedup vs baseline: 1.2835x; 1.0407x over previous
//
#include <hip/hip_runtime.h>
#include <math.h>

#define NPOS 131072  // 8*128*128 spatial positions per (b, channel)
#define GC 128       // gram chunks per (b,head); chunk = 1024 positions

typedef __attribute__((ext_vector_type(8))) short short8v;  // 8 bf16 (4 VGPR)
typedef __attribute__((ext_vector_type(4))) float f32x4;    // 4 fp32 acc

// split fp32 -> bf16 hi + bf16 lo (x ~= hi + lo, lo residual ~2^-16 |x|)
__device__ __forceinline__ void bf16split(float x, unsigned short& hi, unsigned short& lo) {
  unsigned u = __float_as_uint(x);
  hi = (unsigned short)(u >> 16);
  float hif = __uint_as_float(u & 0xffff0000u);
  float l = x - hif;  // exact
  lo = (unsigned short)(__float_as_uint(l) >> 16);
}

// ---------------------------------------------------------------------------
// k_prep: split w_qkv [192 out][64 in] into A-fragment-layout bf16 hi/lo.
// Frag element (g,ot,ks,l,j) <-> W[g*64 + ot*16 + (l&15)][ks*32 + (l>>4)*8 + j].
// ---------------------------------------------------------------------------
__global__ void k_prep(const float* __restrict__ w_qkv, unsigned short* __restrict__ whi,
                       unsigned short* __restrict__ wlo) {
  int idx = blockIdx.x * 256 + threadIdx.x;
  if (idx < 12288) {
    int j = idx & 7, l = (idx >> 3) & 63, ks = (idx >> 9) & 1, ot = (idx >> 10) & 3,
        g = idx >> 12;
    int out = ot * 16 + (l & 15);
    int k = ks * 32 + (l >> 4) * 8 + j;
    bf16split(w_qkv[(g * 64 + out) * 64 + k], whi[idx], wlo[idx]);
  }
}

// ---------------------------------------------------------------------------
// pw_body: shared body for the pointwise MFMA kernels.
// Stage x-tile [64ch][64pos] -> LDS (float4 coalesced); MFMA into D regs;
// bounce D through LDS; cooperative writeout with 4 rows x 256B CONTIGUOUS
// per wave-instr (r15-r19: the scattered 64B channel-stream stores were the
// invariant across five 42us structures; k_dw with full-line writes is fast).
// ---------------------------------------------------------------------------
__device__ __forceinline__ void pw_body(const float* __restrict__ gin,
                                        const short8v* ahi, const short8v* alo,
                                        float* __restrict__ gout, int tid) {
  __shared__ __align__(16) float xl[64][66];
  const int lane = tid & 63;
  const int ot = tid >> 6;
  const int f4 = tid & 15;
  // stage x tile: 1024 float4, coalesced
#pragma unroll
  for (int r = 0; r < 4; ++r) {
    int ch2 = (r * 256 + tid) >> 4;
    float4 g = *(const float4*)&gin[(size_t)ch2 * NPOS + f4 * 4];
    *(float4*)&xl[ch2][f4 * 4] = g;
  }
  __syncthreads();
  const int prow = lane & 15, kgrp = lane >> 4;
  f32x4 Dv[4];
#pragma unroll
  for (int pt = 0; pt < 4; ++pt) {
    const int pos = pt * 16 + prow;
    short8v bh[2], bl[2];
#pragma unroll
    for (int ks = 0; ks < 2; ++ks)
#pragma unroll
      for (int j = 0; j < 8; ++j) {
        unsigned short h, lo16;
        bf16split(xl[ks * 32 + kgrp * 8 + j][pos], h, lo16);
        bh[ks][j] = (short)h;
        bl[ks][j] = (short)lo16;
      }
    f32x4 D = {0.f, 0.f, 0.f, 0.f};
#pragma unroll
    for (int ks = 0; ks < 2; ++ks) {
      D = __builtin_amdgcn_mfma_f32_16x16x32_bf16(ahi[ks], bh[ks], D, 0, 0, 0);
      D = __builtin_amdgcn_mfma_f32_16x16x32_bf16(ahi[ks], bl[ks], D, 0, 0, 0);
      D = __builtin_amdgcn_mfma_f32_16x16x32_bf16(alo[ks], bh[ks], D, 0, 0, 0);
    }
    Dv[pt] = D;
  }
  __syncthreads();  // all waves done reading xl; reuse it as the output tile
#pragma unroll
  for (int pt = 0; pt < 4; ++pt)
#pragma unroll
    for (int jj = 0; jj < 4; ++jj)
      xl[ot * 16 + kgrp * 4 + jj][pt * 16 + prow] = Dv[pt][jj];
  __syncthreads();
  // writeout: wave-instr covers 4 rows x 256B contiguous (full 128B lines)
#pragma unroll
  for (int r = 0; r < 4; ++r) {
    int idx = r * 256 + tid;
    int row = idx >> 4;
    *(float4*)&gout[(size_t)row * NPOS + f4 * 4] = *(const float4*)&xl[row][f4 * 4];
  }
}

// ---------------------------------------------------------------------------
// k_pw_mfma: pre[b][o][p] = sum_k W[o][k] x[b][k][p]. grid (2048, 2), blk 256.
// ---------------------------------------------------------------------------
__global__ __launch_bounds__(256) void k_pw_mfma(const float* __restrict__ x,
                                                 const unsigned short* __restrict__ whi,
                                                 const unsigned short* __restrict__ wlo,
                                                 float* __restrict__ pre) {
  const int b = blockIdx.y;
  const int lane = threadIdx.x & 63;
  const int ot = threadIdx.x >> 6;
  const int p0 = blockIdx.x * 64;
  short8v ahi[2], alo[2];
#pragma unroll
  for (int ks = 0; ks < 2; ++ks) {
    int fi = ((ot * 2 + ks) * 64 + lane) * 8;
    ahi[ks] = *(const short8v*)&whi[fi];
    alo[ks] = *(const short8v*)&wlo[fi];
  }
  pw_body(x + ((size_t)b * 64) * NPOS + p0, ahi, alo,
          pre + ((size_t)b * 64) * NPOS + p0, threadIdx.x);
}

// ---------------------------------------------------------------------------
// stage_tile: one channel's halo tile -> LDS t[10][10][40]. float4 center,
// scalar edges, zero d-halo planes.
// ---------------------------------------------------------------------------
__device__ __forceinline__ void stage_tile(float (*t)[10][40], const float* __restrict__ in,
                                           int h0, int w0, int tid) {
  for (int i = tid; i < 800; i += 256) {
    int j = i & 7, row = i >> 3;
    int h = row % 10, dpl = row / 10;
    int dd = dpl - 1, hh = h0 + h - 1;
    float4 v = make_float4(0.f, 0.f, 0.f, 0.f);
    if (dd >= 0 && dd < 8 && hh >= 0 && hh < 128)
      v = *(const float4*)&in[((size_t)dd * 128 + hh) * 128 + (w0 + j * 4)];
    *(float4*)&t[dpl][h][4 + j * 4] = v;
  }
  for (int i = tid; i < 200; i += 256) {
    int side = i & 1, row = i >> 1;
    int h = row % 10, dpl = row / 10;
    int dd = dpl - 1, hh = h0 + h - 1;
    int ww = side ? (w0 + 32) : (w0 - 1);
    float v = 0.f;
    if (dd >= 0 && dd < 8 && hh >= 0 && hh < 128 && ww >= 0 && ww < 128)
      v = in[((size_t)dd * 128 + hh) * 128 + ww];
    t[dpl][h][side ? 36 : 3] = v;
  }
}

// ---------------------------------------------------------------------------
// conv_droll: d-rolling 3x3x3 conv: 90 LDS reads, 216 FMA for 8 d-outputs.
// ---------------------------------------------------------------------------
__device__ __forceinline__ void conv_droll(const float (*t)[10][40], const float* wk,
                                           int hl, int wl, float* acc) {
#pragma unroll
  for (int d = 0; d < 8; ++d) acc[d] = 0.f;
#pragma unroll
  for (int dpl = 0; dpl < 10; ++dpl) {
#pragma unroll
    for (int kh = 0; kh < 3; ++kh) {
#pragma unroll
      for (int kw = 0; kw < 3; ++kw) {
        float f = t[dpl][hl + kh][3 + wl + kw];
#pragma unroll
        for (int kd = 0; kd < 3; ++kd) {
          const int d = dpl - kd;
          if (d >= 0 && d < 8)
            acc[d] = fmaf(f, wk[(kd * 3 + kh) * 3 + kw], acc[d]);
        }
      }
    }
  }
}

// ---------------------------------------------------------------------------
// k_dw: depthwise 3x3x3 SAME on a 64-channel group. Flat grid 8192,
// XCD-swizzled. block (32, 8). Optional sum-of-squares partials -> nsq.
// ---------------------------------------------------------------------------
__global__ __launch_bounds__(256) void k_dw(const float* __restrict__ pre,
                                            const float* __restrict__ w_dw,
                                            float* __restrict__ conv,
                                            float* __restrict__ nsq, int g) {
  const int id = blockIdx.x;
  const int sid = (id & 7) * 1024 + (id >> 3);
  const int z = sid >> 6, r = sid & 63, by = r >> 2, bx = r & 3;
  const int b = z >> 6;
  const int c = z & 63;
  const int h0 = by * 8;
  const int w0 = bx * 32;
  __shared__ float t[10][10][40];
  __shared__ float red[4];
  const int tid = threadIdx.y * 32 + threadIdx.x;
  stage_tile(t, pre + ((size_t)b * 64 + c) * NPOS, h0, w0, tid);
  float wk[27];
#pragma unroll
  for (int i = 0; i < 27; ++i) wk[i] = w_dw[(g * 64 + c) * 27 + i];
  __syncthreads();
  const int wl = threadIdx.x, hl = threadIdx.y;
  float acc[8];
  conv_droll(t, wk, hl, wl, acc);
  float* outp = conv + ((size_t)b * 64 + c) * NPOS + (size_t)(h0 + hl) * 128 + (w0 + wl);
  float nsum = 0.f;
#pragma unroll
  for (int d = 0; d < 8; ++d) {
    outp[(size_t)d * 16384] = acc[d];
    nsum = fmaf(acc[d], acc[d], nsum);
  }
  if (nsq) {
    const int lane = tid & 63, wv = tid >> 6;
    float v = nsum;
    v += __shfl_down(v, 32); v += __shfl_down(v, 16); v += __shfl_down(v, 8);
    v += __shfl_down(v, 4);  v += __shfl_down(v, 2);  v += __shfl_down(v, 1);
    if (lane == 0) red[wv] = v;
    __syncthreads();
    if (tid == 0) {
      const int blk = by * 4 + bx;
      nsq[((size_t)b * 64 + c) * 64 + blk] = red[0] + red[1] + red[2] + red[3];
    }
  }
}

// ---------------------------------------------------------------------------
// k_gramS: streaming Gram reduce, S[8][8] only (norms come from k_dw).
// grid (GC, 16 bh), block 256; 4 unrolled iterations of {16 loads -> 64 FMA};
// asm guards pin S. Butterfly-split reduction (63 shuffles) -> lane l holds
// wave sum of S[bitrev6(l)]. partialS[(bh*GC + chunk)*64 + c*8+e].
// ---------------------------------------------------------------------------
__global__ __launch_bounds__(256) void k_gramS(const float* __restrict__ qconv,
                                               const float* __restrict__ kconv,
                                               float* __restrict__ partialS) {
  const int chunk = blockIdx.x;   // 0..GC-1
  const int bh = blockIdx.y;      // 0..15
  const int b = bh >> 3, head = bh & 7;
  const int tid = threadIdx.x;
  const size_t base = ((size_t)b * 64 + head * 8) * NPOS + (size_t)chunk * 1024 + tid;
  const float* qb = qconv + base;
  const float* kb = kconv + base;
  float S[64];
#pragma unroll
  for (int i = 0; i < 64; ++i) S[i] = 0.f;
#pragma unroll
  for (int it = 0; it < 4; ++it) {
    const size_t off = (size_t)it * 256;
    float qv[8], kv[8];
#pragma unroll
    for (int c = 0; c < 8; ++c) qv[c] = qb[(size_t)c * NPOS + off];
#pragma unroll
    for (int e = 0; e < 8; ++e) kv[e] = kb[(size_t)e * NPOS + off];
#pragma unroll
    for (int c = 0; c < 8; ++c)
#pragma unroll
      for (int e = 0; e < 8; ++e) S[c * 8 + e] = fmaf(qv[c], kv[e], S[c * 8 + e]);
  }
#pragma unroll
  for (int i = 0; i < 64; ++i) asm volatile("" : "+v"(S[i]));  // keep S material

  const int lane = tid & 63, wv = tid >> 6;
#define BSTEP(src, dst, n, s)                                        \
  {                                                                  \
    const bool hi_ = (lane >> (s)) & 1;                              \
    _Pragma("unroll")                                                \
    for (int i_ = 0; i_ < (n); ++i_) {                               \
      float send_ = hi_ ? src[i_] : src[i_ + (n)];                   \
      float mine_ = hi_ ? src[i_ + (n)] : src[i_];                   \
      dst[i_] = mine_ + __shfl_xor(send_, 1 << (s));                 \
    }                                                                \
  }
  float v32[32], v16[16], v8[8], v4[4], v2[2], v1[1];
  BSTEP(S,   v32, 32, 0)
  BSTEP(v32, v16, 16, 1)
  BSTEP(v16, v8,   8, 2)
  BSTEP(v8,  v4,   4, 3)
  BSTEP(v4,  v2,   2, 4)
  BSTEP(v2,  v1,   1, 5)
#undef BSTEP
  const int idx = ((lane & 1) << 5) | ((lane & 2) << 3) | ((lane & 4) << 1) |
                  ((lane & 8) >> 1) | ((lane & 16) >> 3) | ((lane & 32) >> 5);
  __shared__ float red[4][64];
  red[wv][idx] = v1[0];
  __syncthreads();
  if (tid < 64) {
    float s = red[0][tid] + red[1][tid] + red[2][tid] + red[3][tid];
    partialS[((size_t)bh * GC + chunk) * 64 + tid] = s;
  }
}

// ---------------------------------------------------------------------------
// k_attn: reduce partialS (GC chunks) + nqp/nkp (64 spatial blocks),
// l2-normalize, temperature, softmax -> A[bh][c][e]. grid 16, block 128.
// ---------------------------------------------------------------------------
__global__ void k_attn(const float* __restrict__ partialS, const float* __restrict__ nqp,
                       const float* __restrict__ nkp, const float* __restrict__ temp,
                       float* __restrict__ A) {
  const int bh = blockIdx.x;
  const int b = bh >> 3, head = bh & 7;
  const int tid = threadIdx.x;
  __shared__ float sums[80];
  if (tid < 64) {
    float s = 0.f;
    const float* pp = partialS + (size_t)bh * GC * 64 + tid;
    for (int j = 0; j < GC; ++j) s += pp[j * 64];
    sums[tid] = s;  // S[c*8+e]
  } else if (tid < 72) {
    const int e = tid - 64;
    float s = 0.f;
    const float* pp = nkp + ((size_t)b * 64 + head * 8 + e) * 64;
    for (int j = 0; j < 64; ++j) s += pp[j];
    sums[64 + e] = s;  // nk[e]
  } else if (tid < 80) {
    const int c = tid - 72;
    float s = 0.f;
    const float* pp = nqp + ((size_t)b * 64 + head * 8 + c) * 64;
    for (int j = 0; j < 64; ++j) s += pp[j];
    sums[72 + c] = s;  // nq[c]
  }
  __syncthreads();
  if (tid < 8) {
    const int c = tid;
    float tp = temp[head];
    float qd = fmaxf(sqrtf(sums[72 + c]), 1e-12f);
    float vals[8];
    float mx = -1e30f;
#pragma unroll
    for (int e = 0; e < 8; ++e) {
      float kd = fmaxf(sqrtf(sums[64 + e]), 1e-12f);
      vals[e] = sums[c * 8 + e] / (qd * kd) * tp;
      mx = fmaxf(mx, vals[e]);
    }
    float den = 0.f;
#pragma unroll
    for (int e = 0; e < 8; ++e) { vals[e] = expf(vals[e] - mx); den += vals[e]; }
#pragma unroll
    for (int e = 0; e < 8; ++e) A[bh * 64 + c * 8 + e] = vals[e] / den;
  }
}

// ---------------------------------------------------------------------------
// k_M: M_b = W_proj x blockdiag(softmax A_b), written directly in A-fragment
// bf16 hi/lo layout for k_out_mfma. grid 2, block 256.
// ---------------------------------------------------------------------------
__global__ void k_M(const float* __restrict__ w_proj, const float* __restrict__ A,
                    unsigned short* __restrict__ Mhi, unsigned short* __restrict__ Mlo) {
  const int b = blockIdx.x;
  for (int e = threadIdx.x; e < 4096; e += 256) {
    int j = e & 7, l = (e >> 3) & 63, ks = (e >> 9) & 1, ot = (e >> 10) & 3;
    int out = ot * 16 + (l & 15);
    int gch = ks * 32 + (l >> 4) * 8 + j;
    int hg = gch >> 3, jj = gch & 7;
    float s = 0.f;
#pragma unroll
    for (int i = 0; i < 8; ++i)
      s += w_proj[out * 64 + hg * 8 + i] * A[(b * 8 + hg) * 64 + i * 8 + jj];
    bf16split(s, Mhi[b * 4096 + e], Mlo[b * 4096 + e]);
  }
}

// ---------------------------------------------------------------------------
// k_out_mfma: out[b][o][p] = sum_g M_b[o][g] vconv[b][g][p]. Same LDS-bounce
// structure as k_pw_mfma. grid (2048, 2), block 256.
// ---------------------------------------------------------------------------
__global__ __launch_bounds__(256) void k_out_mfma(const float* __restrict__ vconv,
                                                  const unsigned short* __restrict__ Mhi,
                                                  const unsigned short* __restrict__ Mlo,
                                                  float* __restrict__ out) {
  const int b = blockIdx.y;
  const int lane = threadIdx.x & 63;
  const int ot = threadIdx.x >> 6;
  const int p0 = blockIdx.x * 64;
  short8v ahi[2], alo[2];
#pragma unroll
  for (int ks = 0; ks < 2; ++ks) {
    int fi = b * 4096 + ((ot * 2 + ks) * 64 + lane) * 8;
    ahi[ks] = *(const short8v*)&Mhi[fi];
    alo[ks] = *(const short8v*)&Mlo[fi];
  }
  pw_body(vconv + ((size_t)b * 64) * NPOS + p0, ahi, alo,
          out + ((size_t)b * 64) * NPOS + p0, threadIdx.x);
}

extern "C" void kernel_launch(void* const* d_in, const int* in_sizes, int n_in,
                              void* d_out, int out_size, void* d_ws, size_t ws_size,
                              hipStream_t stream) {
  const float* x      = (const float*)d_in[0];
  const float* w_qkv  = (const float*)d_in[1];
  const float* w_dw   = (const float*)d_in[2];
  const float* temp   = (const float*)d_in[3];
  const float* w_proj = (const float*)d_in[4];
  float* out = (float*)d_out;   // also used as pre-conv staging per group
  float* ws  = (float*)d_ws;

  // workspace layout — ~135 MB (r16 layout; produce->consume order keeps each
  // 67 MB tensor L3-resident between stages — r17 proved fusing breaks this)
  float* conv_buf = ws;                       // qconv, later vconv (67 MB)
  float* kconv    = conv_buf + 16777216ull;   // 67 MB
  float* nqp      = kconv + 16777216ull;      // 8,192
  float* nkp      = nqp + 8192ull;            // 8,192
  float* partialS = nkp + 8192ull;            // 16*GC*64 = 131,072
  float* Abuf     = partialS + 131072ull;     // 1,024
  unsigned short* whi = (unsigned short*)(Abuf + 1024ull);  // 12,288 us
  unsigned short* wlo = whi + 12288ull;                     // 12,288 us
  unsigned short* Mhi = wlo + 12288ull;                     // 8,192 us
  unsigned short* Mlo = Mhi + 8192ull;                      // 8,192 us

  k_prep<<<48, 256, 0, stream>>>(w_qkv, whi, wlo);
  // q group: pointwise (MFMA) -> d_out, depthwise -> conv_buf (+ nq partials)
  k_pw_mfma<<<dim3(2048, 2), 256, 0, stream>>>(x, whi, wlo, out);
  k_dw<<<8192, dim3(32, 8), 0, stream>>>(out, w_dw, conv_buf, nqp, 0);
  // k group: pointwise -> d_out, depthwise -> kconv (+ nk partials)
  k_pw_mfma<<<dim3(2048, 2), 256, 0, stream>>>(x, whi + 4096, wlo + 4096, out);
  k_dw<<<8192, dim3(32, 8), 0, stream>>>(out, w_dw, kconv, nkp, 1);
  // Gram + attention matrix + folded projection matrix (frag layout)
  k_gramS<<<dim3(GC, 16), 256, 0, stream>>>(conv_buf, kconv, partialS);
  k_attn<<<16, 128, 0, stream>>>(partialS, nqp, nkp, temp, Abuf);
  k_M<<<2, 256, 0, stream>>>(w_proj, Abuf, Mhi, Mlo);
  // v group: pointwise -> d_out, depthwise -> conv_buf, apply M (MFMA) -> d_out
  k_pw_mfma<<<dim3(2048, 2), 256, 0, stream>>>(x, whi + 8192, wlo + 8192, out);
  k_dw<<<8192, dim3(32, 8), 0, stream>>>(out, w_dw, conv_buf, nullptr, 2);
  k_out_mfma<<<dim3(2048, 2), 256, 0, stream>>>(conv_buf, Mhi, Mlo, out);
}